// Round 17
// baseline (361.238 us; speedup 1.0000x reference)
//
#include <hip/hip_runtime.h>
#include <hip/hip_fp16.h>

typedef __attribute__((ext_vector_type(8))) _Float16 f16x8;
typedef __attribute__((ext_vector_type(4))) float f32x4;

#define M_DIM 8192
#define N_DIM 4096
#define K_DIM 4096
#define BM 128
#define BN 128
#define BK 64
#define NT (K_DIM / BK)      // 64 K-tiles
#define ITERS (NT / 2)       // 32 iterations, 2 tiles each

__constant__ float FP4_LUT[16] = {0.f, 0.5f, 1.f, 1.5f, 2.f, 3.f, 4.f, 6.f,
                                  -0.f, -0.5f, -1.f, -1.5f, -2.f, -3.f, -4.f, -6.f};

__device__ inline void glds16(const void* g, void* l) {
    __builtin_amdgcn_global_load_lds(
        (const __attribute__((address_space(1))) void*)g,
        (__attribute__((address_space(3))) void*)l, 16, 0, 0);
}

// ---- merged prepass: blocks [0,16384) convert x; [16384,24576) dequant W ----
__global__ __launch_bounds__(256) void prep_kernel(const float* __restrict__ x,
                                                   _Float16* __restrict__ xh,
                                                   const int* __restrict__ w,
                                                   const float* __restrict__ wsc,
                                                   _Float16* __restrict__ wh) {
    int b = blockIdx.x;
    if (b < 16384) {
        int i = (b * 256 + threadIdx.x) * 8;
        const float4* p = (const float4*)(x + i);
        float4 a = p[0], c = p[1];
        f16x8 h;
        h[0] = (_Float16)a.x; h[1] = (_Float16)a.y;
        h[2] = (_Float16)a.z; h[3] = (_Float16)a.w;
        h[4] = (_Float16)c.x; h[5] = (_Float16)c.y;
        h[6] = (_Float16)c.z; h[7] = (_Float16)c.w;
        *(f16x8*)(xh + i) = h;
    } else {
        int t = (b - 16384) * 256 + threadIdx.x;   // one thread = 4 int32 = 8 fp4
        int4 b4 = ((const int4*)w)[t];
        int o  = t >> 9;
        int j0 = (t & 511) << 2;
        float s = wsc[(o << 8) + (j0 >> 3)];
        f16x8 h;
        int v;
        v = b4.x; h[0] = (_Float16)(FP4_LUT[(v >> 4) & 15] * s); h[1] = (_Float16)(FP4_LUT[v & 15] * s);
        v = b4.y; h[2] = (_Float16)(FP4_LUT[(v >> 4) & 15] * s); h[3] = (_Float16)(FP4_LUT[v & 15] * s);
        v = b4.z; h[4] = (_Float16)(FP4_LUT[(v >> 4) & 15] * s); h[5] = (_Float16)(FP4_LUT[v & 15] * s);
        v = b4.w; h[6] = (_Float16)(FP4_LUT[(v >> 4) & 15] * s); h[7] = (_Float16)(FP4_LUT[v & 15] * s);
        *(f16x8*)(wh + ((long)o << 12) + (j0 << 1)) = h;
    }
}

// ====== 128x128 GEMM, r13 engine, 2 blocks/CU for cross-block pipe overlap (r17) ======
// Same schedule family as r13 (proven: conflicts 0, waits minimal) rescaled:
// 4 waves (2x2, 64x64/wave), LDS 2buf x 32KB = 64KB -> 2 independent barrier
// domains per CU; m114: separate waves overlap pipes fully (time ~= max).
// Per phase: af 2 reads; bf 4 on odd phases; 8 MFMA; LG2@even / LG6@odd
// (retire exactly prev phase's reads); VM4@odd + barrier (stage units still
// 2 glds each -> identical RAW/WAR ledger to r13).

#define VM4 asm volatile("s_waitcnt vmcnt(4)" ::: "memory")
#define VM0 asm volatile("s_waitcnt vmcnt(0)" ::: "memory")
#define LG6 asm volatile("s_waitcnt lgkmcnt(6)" ::: "memory")
#define LG2 asm volatile("s_waitcnt lgkmcnt(2)" ::: "memory")
#define LG0 asm volatile("s_waitcnt lgkmcnt(0)" ::: "memory")
#define NOP ((void)0)

#define STAGE(OP, SD, KH, KOFF) do {                                           \
    _Float16* _d = lds + (SD)*16384 + (OP)*8192 + (KH)*4096 + (wid << 9);      \
    const _Float16* _s = ((OP) ? srcB : srcA) + (KOFF);                        \
    glds16(_s, _d);                                                            \
    glds16(_s + (size_t)64 * K_DIM, _d + 2048);                                \
  } while (0)

#define PH(DOAF, NCB, NKH, NMH, AFN, DOBF, BFN, LGW, MHC, AFC, BFC, STG, VMW, BAR) do { \
    STG;                                                                       \
    const _Float16* _nb = lds + (NCB)*16384 + (NKH)*4096;                      \
    if (DOAF) {                                                                \
      AFN[0] = *(const f16x8*)(_nb + a_off + (NMH)*1024);                      \
      AFN[1] = *(const f16x8*)(_nb + a_off + (NMH)*1024 + 512);                \
    }                                                                          \
    if (DOBF) {                                                                \
      BFN[0] = *(const f16x8*)(_nb + b_off);                                   \
      BFN[1] = *(const f16x8*)(_nb + b_off + 512);                             \
      BFN[2] = *(const f16x8*)(_nb + b_off + 1024);                            \
      BFN[3] = *(const f16x8*)(_nb + b_off + 1536);                            \
    }                                                                          \
    LGW;                                                                       \
    __builtin_amdgcn_s_setprio(1);                                             \
    _Pragma("unroll")                                                          \
    for (int mf = 0; mf < 2; ++mf) {                                           \
      _Pragma("unroll")                                                        \
      for (int nf = 0; nf < 4; ++nf)                                           \
        acc[(MHC)*2 + mf][nf] = __builtin_amdgcn_mfma_f32_16x16x32_f16(        \
            AFC[mf], BFC[nf], acc[(MHC)*2 + mf][nf], 0, 0, 0);                 \
    }                                                                          \
    __builtin_amdgcn_s_setprio(0);                                             \
    VMW;                                                                       \
    if (BAR) __builtin_amdgcn_s_barrier();                                     \
  } while (0)

__global__ __launch_bounds__(256, 2) void gemm_f16_pf(const _Float16* __restrict__ A,
                                                      const _Float16* __restrict__ B,
                                                      const float* __restrict__ bias,
                                                      float* __restrict__ C) {
    __shared__ _Float16 lds[2 * 16384];   // 64 KiB -> 2 blocks/CU

    const int tid  = threadIdx.x;
    const int wid  = tid >> 6;
    const int lane = tid & 63;
    const int fr   = lane & 15;
    const int kg   = lane >> 4;
    const int wm   = wid >> 1;     // 0..1
    const int wn   = wid & 1;      // 0..1

    // XCD swizzle: 2048 blocks, 256/XCD, square 16bm x 16bn chunk, bm-fast
    const int c = blockIdx.x & 7;
    const int q = blockIdx.x >> 3;            // 0..255
    const int bm = (c >> 1) * 16 + (q & 15);  // 0..63
    const int bn = (c & 1) * 16 + (q >> 4);   // 0..31
    const int brow = bm * BM;
    const int bcol = bn * BN;

    // staging source: row tid>>2 (0..63); pre-swizzled col slot (rule #21)
    const int s_col = (((tid & 3) ^ ((tid >> 3) & 3)) << 3);
    const _Float16* srcA = A + (size_t)(brow + (tid >> 2)) * K_DIM + s_col;
    const _Float16* srcB = B + (size_t)(bcol + (tid >> 2)) * K_DIM + s_col;

    // ds_read offsets: row*32 + swizzled 16B slot (r13 geometry, conflicts 0)
    const int swz   = ((kg ^ ((fr >> 1) & 3)) << 3);
    const int a_off = (wm * 64 + fr) * 32 + swz;
    const int b_off = 8192 + (wn * 64 + fr) * 32 + swz;

    f16x8 af0[2], af1[2], bf0[4], bf1[4];
    f32x4 acc[4][4] = {};

    // prologue: 6 stage units (t0 full + t1.kh0); VM4 retires units 1-4.
    STAGE(0, 0, 0, 0);
    STAGE(1, 0, 0, 0);
    STAGE(0, 0, 1, 32);
    STAGE(1, 0, 1, 32);
    STAGE(0, 1, 0, 64);
    STAGE(1, 1, 0, 64);
    VM4;
    __builtin_amdgcn_s_barrier();
    // preload phase-0 operands: buf0.kh0 mh0 + B
    af0[0] = *(const f16x8*)(lds + a_off);
    af0[1] = *(const f16x8*)(lds + a_off + 512);
    bf0[0] = *(const f16x8*)(lds + b_off);
    bf0[1] = *(const f16x8*)(lds + b_off + 512);
    bf0[2] = *(const f16x8*)(lds + b_off + 1024);
    bf0[3] = *(const f16x8*)(lds + b_off + 1536);

    for (int i = 0; i < ITERS - 1; ++i) {
        const int kb = i << 7;
        PH(1, 0,0,1, af1, 0,bf0, LG2, 0, af0, bf0, STAGE(0,1,1,kb+96),  NOP, 0); // p0
        PH(1, 0,1,0, af0, 1,bf1, LG6, 1, af1, bf0, STAGE(1,1,1,kb+96),  VM4, 1); // p1
        PH(1, 0,1,1, af1, 0,bf0, LG2, 0, af0, bf1, STAGE(0,0,0,kb+128), NOP, 0); // p2
        PH(1, 1,0,0, af0, 1,bf0, LG6, 1, af1, bf1, STAGE(1,0,0,kb+128), VM4, 1); // p3
        PH(1, 1,0,1, af1, 0,bf0, LG2, 0, af0, bf0, STAGE(0,0,1,kb+160), NOP, 0); // p4
        PH(1, 1,1,0, af0, 1,bf1, LG6, 1, af1, bf0, STAGE(1,0,1,kb+160), VM4, 1); // p5
        PH(1, 1,1,1, af1, 0,bf0, LG2, 0, af0, bf1, STAGE(0,1,0,kb+192), NOP, 0); // p6
        PH(1, 0,0,0, af0, 1,bf0, LG6, 1, af1, bf1, STAGE(1,1,0,kb+192), VM4, 1); // p7
    }
    {   // drain iteration (tiles NT-2, NT-1): only t+1.kh1 staging remains
        const int kb = (ITERS - 1) << 7;
        PH(1, 0,0,1, af1, 0,bf0, LG2, 0, af0, bf0, STAGE(0,1,1,kb+96), NOP, 0); // p0
        PH(1, 0,1,0, af0, 1,bf1, LG6, 1, af1, bf0, STAGE(1,1,1,kb+96), VM4, 1); // p1
        PH(1, 0,1,1, af1, 0,bf0, LG2, 0, af0, bf1, NOP,                NOP, 0); // p2
        PH(1, 1,0,0, af0, 1,bf0, LG6, 1, af1, bf1, NOP,                VM0, 1); // p3
        PH(1, 1,0,1, af1, 0,bf0, LG2, 0, af0, bf0, NOP,                NOP, 0); // p4
        PH(1, 1,1,0, af0, 1,bf1, LG6, 1, af1, bf0, NOP,                NOP, 1); // p5
        PH(1, 1,1,1, af1, 0,bf0, LG2, 0, af0, bf1, NOP,                NOP, 0); // p6
        PH(0, 0,0,0, af0, 0,bf0, LG0, 1, af1, bf1, NOP,                NOP, 0); // p7
    }

    // epilogue: C/D layout col = lane&15, row = (lane>>4)*4 + reg
#pragma unroll
    for (int m = 0; m < 4; ++m) {
        int row = brow + wm * 64 + m * 16 + kg * 4;
#pragma unroll
        for (int n = 0; n < 4; ++n) {
            int col = bcol + wn * 64 + n * 16 + fr;
            float bv = bias[col];
#pragma unroll
            for (int j = 0; j < 4; ++j)
                C[(size_t)(row + j) * N_DIM + col] = acc[m][n][j] + bv;
        }
    }
}

// ---- fallback (only if ws too small) ----
__global__ __launch_bounds__(256) void fallback_kernel(const float* __restrict__ x,
                                                       const int* __restrict__ w,
                                                       const float* __restrict__ wsc,
                                                       const float* __restrict__ bias,
                                                       float* __restrict__ out) {
    long idx = (long)blockIdx.x * 256 + threadIdx.x;
    int t = (int)(idx >> 12);
    int o = (int)(idx & 4095);
    float acc = 0.f;
    for (int j = 0; j < K_DIM / 2; ++j) {
        int b = w[o * (K_DIM / 2) + j];
        float s = wsc[(o << 8) + (j >> 3)];
        acc += x[(long)t * K_DIM + 2 * j]     * (FP4_LUT[(b >> 4) & 15] * s);
        acc += x[(long)t * K_DIM + 2 * j + 1] * (FP4_LUT[b & 15] * s);
    }
    out[idx] = acc + bias[o];
}

extern "C" void kernel_launch(void* const* d_in, const int* in_sizes, int n_in,
                              void* d_out, int out_size, void* d_ws, size_t ws_size,
                              hipStream_t stream) {
    const float* x    = (const float*)d_in[0];
    const int*   w    = (const int*)d_in[1];
    const float* wsc  = (const float*)d_in[2];
    const float* bias = (const float*)d_in[3];
    float* out = (float*)d_out;

    const size_t xh_bytes = (size_t)M_DIM * K_DIM * 2;   // 64 MB
    const size_t wh_bytes = (size_t)N_DIM * K_DIM * 2;   // 32 MB

    if (ws_size >= xh_bytes + wh_bytes) {
        _Float16* xh = (_Float16*)d_ws;
        _Float16* wh = (_Float16*)((char*)d_ws + xh_bytes);
        prep_kernel<<<16384 + 8192, 256, 0, stream>>>(x, xh, w, wsc, wh);
        gemm_f16_pf<<<(M_DIM / BM) * (N_DIM / BN), 256, 0, stream>>>(xh, wh, bias, out);
    } else {
        fallback_kernel<<<((long)M_DIM * N_DIM) / 256, 256, 0, stream>>>(x, w, wsc, bias, out);
    }
}

// Round 18
// 275.682 us; speedup vs baseline: 1.3103x; 1.3103x over previous
//
#include <hip/hip_runtime.h>
#include <hip/hip_fp16.h>

typedef __attribute__((ext_vector_type(8))) _Float16 f16x8;
typedef __attribute__((ext_vector_type(4))) float f32x4;

#define M_DIM 8192
#define N_DIM 4096
#define K_DIM 4096
#define BM 256
#define BN 256
#define BK 64
#define NT (K_DIM / BK)      // 64 K-tiles
#define ITERS (NT / 2)       // 32 iterations, 2 tiles each

__constant__ float FP4_LUT[16] = {0.f, 0.5f, 1.f, 1.5f, 2.f, 3.f, 4.f, 6.f,
                                  -0.f, -0.5f, -1.f, -1.5f, -2.f, -3.f, -4.f, -6.f};

__device__ inline void glds16(const void* g, void* l) {
    __builtin_amdgcn_global_load_lds(
        (const __attribute__((address_space(1))) void*)g,
        (__attribute__((address_space(3))) void*)l, 16, 0, 0);
}

// ---- merged prepass: blocks [0,16384) convert x; [16384,24576) dequant W ----
__global__ __launch_bounds__(256) void prep_kernel(const float* __restrict__ x,
                                                   _Float16* __restrict__ xh,
                                                   const int* __restrict__ w,
                                                   const float* __restrict__ wsc,
                                                   _Float16* __restrict__ wh) {
    int b = blockIdx.x;
    if (b < 16384) {
        int i = (b * 256 + threadIdx.x) * 8;
        const float4* p = (const float4*)(x + i);
        float4 a = p[0], c = p[1];
        f16x8 h;
        h[0] = (_Float16)a.x; h[1] = (_Float16)a.y;
        h[2] = (_Float16)a.z; h[3] = (_Float16)a.w;
        h[4] = (_Float16)c.x; h[5] = (_Float16)c.y;
        h[6] = (_Float16)c.z; h[7] = (_Float16)c.w;
        *(f16x8*)(xh + i) = h;
    } else {
        int t = (b - 16384) * 256 + threadIdx.x;   // one thread = 4 int32 = 8 fp4
        int4 b4 = ((const int4*)w)[t];
        int o  = t >> 9;
        int j0 = (t & 511) << 2;
        float s = wsc[(o << 8) + (j0 >> 3)];
        f16x8 h;
        int v;
        v = b4.x; h[0] = (_Float16)(FP4_LUT[(v >> 4) & 15] * s); h[1] = (_Float16)(FP4_LUT[v & 15] * s);
        v = b4.y; h[2] = (_Float16)(FP4_LUT[(v >> 4) & 15] * s); h[3] = (_Float16)(FP4_LUT[v & 15] * s);
        v = b4.z; h[4] = (_Float16)(FP4_LUT[(v >> 4) & 15] * s); h[5] = (_Float16)(FP4_LUT[v & 15] * s);
        v = b4.w; h[6] = (_Float16)(FP4_LUT[(v >> 4) & 15] * s); h[7] = (_Float16)(FP4_LUT[v & 15] * s);
        *(f16x8*)(wh + ((long)o << 12) + (j0 << 1)) = h;
    }
}

// ====== 256x256 GEMM, 1-phase register prefetch + half barriers (r13 engine, FINAL) ======
// Verified best (r13/r16 reproduced): GEMM 229 us @ MfmaUtil 58%, conflicts 0,
// FETCH 197MB, total 276.6 us. Closed levers (all measured): full-barrier
// 8-phase ~50% (r4-r6); 32x32 shape — r9/r14 conflicts, r15 staging scatter
// ({linear glds dest, coalesced src, clean b128 frags} unsatisfiable);
// 2-deep prefetch spills (r12); 128^2 tile / 2 blocks/CU −42% (r17);
// fp8/MX fails absmax budget by arithmetic. Residual gap = LDS<->MFMA
// alternation within one barrier domain (hand-asm-schedule territory).
// Phase: {stage glds | prefetch next phase's frags | LG retiring prev-phase
// reads | 16 MFMA on prev-phase regs | [VM4 + barrier on odd phases]}.
// RAW: VM4@odd retires stages >=2 phases old, published by that barrier, read
// >=1 barrier later. WAR: LG4/LG8 bound read-retire to <=1 phase, sealed by
// the next odd barrier. T2 XOR swizzle both-sides (rule #21); square XCD chunks.

#define VM4 asm volatile("s_waitcnt vmcnt(4)" ::: "memory")
#define VM0 asm volatile("s_waitcnt vmcnt(0)" ::: "memory")
#define LG8 asm volatile("s_waitcnt lgkmcnt(8)" ::: "memory")
#define LG4 asm volatile("s_waitcnt lgkmcnt(4)" ::: "memory")
#define LG0 asm volatile("s_waitcnt lgkmcnt(0)" ::: "memory")
#define NOP ((void)0)

#define STAGE(OP, SD, KH, KOFF) do {                                           \
    _Float16* _d = lds + (SD)*32768 + (OP)*16384 + (KH)*8192 + (wid << 9);     \
    const _Float16* _s = ((OP) ? srcB : srcA) + (KOFF);                        \
    glds16(_s, _d);                                                            \
    glds16(_s + (size_t)128 * K_DIM, _d + 4096);                               \
  } while (0)

#define PH(DOAF, NCB, NKH, NMH, AFN, DOBF, BFN, LGW, MHC, AFC, BFC, STG, VMW, BAR) do { \
    STG;                                                                       \
    const _Float16* _nb = lds + (NCB)*32768 + (NKH)*8192;                      \
    if (DOAF) {                                                                \
      AFN[0] = *(const f16x8*)(_nb + a_off + (NMH)*2048);                      \
      AFN[1] = *(const f16x8*)(_nb + a_off + (NMH)*2048 + 512);                \
      AFN[2] = *(const f16x8*)(_nb + a_off + (NMH)*2048 + 1024);               \
      AFN[3] = *(const f16x8*)(_nb + a_off + (NMH)*2048 + 1536);               \
    }                                                                          \
    if (DOBF) {                                                                \
      BFN[0] = *(const f16x8*)(_nb + b_off);                                   \
      BFN[1] = *(const f16x8*)(_nb + b_off + 512);                             \
      BFN[2] = *(const f16x8*)(_nb + b_off + 1024);                            \
      BFN[3] = *(const f16x8*)(_nb + b_off + 1536);                            \
    }                                                                          \
    LGW;                                                                       \
    __builtin_amdgcn_s_setprio(1);                                             \
    _Pragma("unroll")                                                          \
    for (int mf = 0; mf < 4; ++mf) {                                           \
      _Pragma("unroll")                                                        \
      for (int nf = 0; nf < 4; ++nf)                                           \
        acc[(MHC)*4 + mf][nf] = __builtin_amdgcn_mfma_f32_16x16x32_f16(        \
            AFC[mf], BFC[nf], acc[(MHC)*4 + mf][nf], 0, 0, 0);                 \
    }                                                                          \
    __builtin_amdgcn_s_setprio(0);                                             \
    VMW;                                                                       \
    if (BAR) __builtin_amdgcn_s_barrier();                                     \
  } while (0)

__global__ __launch_bounds__(512, 2) void gemm_f16_pf(const _Float16* __restrict__ A,
                                                      const _Float16* __restrict__ B,
                                                      const float* __restrict__ bias,
                                                      float* __restrict__ C) {
    __shared__ _Float16 lds[2 * 32768];   // 128 KiB

    const int tid  = threadIdx.x;
    const int wid  = tid >> 6;
    const int lane = tid & 63;
    const int fr   = lane & 15;
    const int kg   = lane >> 4;
    const int wm   = wid >> 2;     // 0..1
    const int wn   = wid & 3;      // 0..3

    // square XCD chunks: 8bm x 8bn per XCD (r7: FETCH 650->198 MB)
    const int c = blockIdx.x & 7;
    const int q = blockIdx.x >> 3;           // 0..63
    const int bm = (c >> 1) * 8 + (q & 7);   // 0..31
    const int bn = (c & 1) * 8 + (q >> 3);   // 0..15
    const int brow = bm * BM;
    const int bcol = bn * BN;

    // staging source: row tid>>2; pre-swizzled col slot (rule #21)
    const int s_col = (((tid & 3) ^ ((tid >> 3) & 3)) << 3);
    const _Float16* srcA = A + (size_t)(brow + (tid >> 2)) * K_DIM + s_col;
    const _Float16* srcB = B + (size_t)(bcol + (tid >> 2)) * K_DIM + s_col;

    // ds_read offsets: row*32 + swizzled 16B slot
    const int swz   = ((kg ^ ((fr >> 1) & 3)) << 3);
    const int a_off = (wm * 128 + fr) * 32 + swz;
    const int b_off = 16384 + (wn * 64 + fr) * 32 + swz;

    f16x8 af0[4], af1[4], bf0[4], bf1[4];
    f32x4 acc[8][4] = {};

    // prologue: 6 stage units; VM4 retires units 1-4 (buf0 complete).
    // buf1.kh0 (units 5,6) retired by VM4@p1 before its p3 readers.
    STAGE(0, 0, 0, 0);
    STAGE(1, 0, 0, 0);
    STAGE(0, 0, 1, 32);
    STAGE(1, 0, 1, 32);
    STAGE(0, 1, 0, 64);
    STAGE(1, 1, 0, 64);
    VM4;
    __builtin_amdgcn_s_barrier();
    // prefetch phase-0 operands: buf0.kh0, m-half 0 + B
    af0[0] = *(const f16x8*)(lds + a_off);
    af0[1] = *(const f16x8*)(lds + a_off + 512);
    af0[2] = *(const f16x8*)(lds + a_off + 1024);
    af0[3] = *(const f16x8*)(lds + a_off + 1536);
    bf0[0] = *(const f16x8*)(lds + b_off);
    bf0[1] = *(const f16x8*)(lds + b_off + 512);
    bf0[2] = *(const f16x8*)(lds + b_off + 1024);
    bf0[3] = *(const f16x8*)(lds + b_off + 1536);

    for (int i = 0; i < ITERS - 1; ++i) {
        const int kb = i << 7;
        PH(1, 0,0,1, af1, 0,bf0, LG4, 0, af0, bf0, STAGE(0,1,1,kb+96),  NOP, 0); // p0
        PH(1, 0,1,0, af0, 1,bf1, LG8, 1, af1, bf0, STAGE(1,1,1,kb+96),  VM4, 1); // p1
        PH(1, 0,1,1, af1, 0,bf0, LG4, 0, af0, bf1, STAGE(0,0,0,kb+128), NOP, 0); // p2
        PH(1, 1,0,0, af0, 1,bf0, LG8, 1, af1, bf1, STAGE(1,0,0,kb+128), VM4, 1); // p3
        PH(1, 1,0,1, af1, 0,bf0, LG4, 0, af0, bf0, STAGE(0,0,1,kb+160), NOP, 0); // p4
        PH(1, 1,1,0, af0, 1,bf1, LG8, 1, af1, bf0, STAGE(1,0,1,kb+160), VM4, 1); // p5
        PH(1, 1,1,1, af1, 0,bf0, LG4, 0, af0, bf1, STAGE(0,1,0,kb+192), NOP, 0); // p6
        PH(1, 0,0,0, af0, 1,bf0, LG8, 1, af1, bf1, STAGE(1,1,0,kb+192), VM4, 1); // p7
    }
    {   // drain iteration (tiles NT-2, NT-1): only t+1.kh1 staging remains
        const int kb = (ITERS - 1) << 7;
        PH(1, 0,0,1, af1, 0,bf0, LG4, 0, af0, bf0, STAGE(0,1,1,kb+96), NOP, 0); // p0
        PH(1, 0,1,0, af0, 1,bf1, LG8, 1, af1, bf0, STAGE(1,1,1,kb+96), VM4, 1); // p1
        PH(1, 0,1,1, af1, 0,bf0, LG4, 0, af0, bf1, NOP,                NOP, 0); // p2
        PH(1, 1,0,0, af0, 1,bf0, LG8, 1, af1, bf1, NOP,                VM0, 1); // p3
        PH(1, 1,0,1, af1, 0,bf0, LG4, 0, af0, bf0, NOP,                NOP, 0); // p4
        PH(1, 1,1,0, af0, 1,bf1, LG8, 1, af1, bf0, NOP,                NOP, 1); // p5
        PH(1, 1,1,1, af1, 0,bf0, LG4, 0, af0, bf1, NOP,                NOP, 0); // p6
        PH(0, 0,0,0, af0, 0,bf0, LG0, 1, af1, bf1, NOP,                NOP, 0); // p7
    }

    // epilogue: C/D layout col = lane&15, row = (lane>>4)*4 + reg
#pragma unroll
    for (int m = 0; m < 8; ++m) {
        int row = brow + wm * 128 + m * 16 + kg * 4;
#pragma unroll
        for (int n = 0; n < 4; ++n) {
            int col = bcol + wn * 64 + n * 16 + fr;
            float bv = bias[col];
#pragma unroll
            for (int j = 0; j < 4; ++j)
                C[(size_t)(row + j) * N_DIM + col] = acc[m][n][j] + bv;
        }
    }
}

// ---- fallback (only if ws too small) ----
__global__ __launch_bounds__(256) void fallback_kernel(const float* __restrict__ x,
                                                       const int* __restrict__ w,
                                                       const float* __restrict__ wsc,
                                                       const float* __restrict__ bias,
                                                       float* __restrict__ out) {
    long idx = (long)blockIdx.x * 256 + threadIdx.x;
    int t = (int)(idx >> 12);
    int o = (int)(idx & 4095);
    float acc = 0.f;
    for (int j = 0; j < K_DIM / 2; ++j) {
        int b = w[o * (K_DIM / 2) + j];
        float s = wsc[(o << 8) + (j >> 3)];
        acc += x[(long)t * K_DIM + 2 * j]     * (FP4_LUT[(b >> 4) & 15] * s);
        acc += x[(long)t * K_DIM + 2 * j + 1] * (FP4_LUT[b & 15] * s);
    }
    out[idx] = acc + bias[o];
}

extern "C" void kernel_launch(void* const* d_in, const int* in_sizes, int n_in,
                              void* d_out, int out_size, void* d_ws, size_t ws_size,
                              hipStream_t stream) {
    const float* x    = (const float*)d_in[0];
    const int*   w    = (const int*)d_in[1];
    const float* wsc  = (const float*)d_in[2];
    const float* bias = (const float*)d_in[3];
    float* out = (float*)d_out;

    const size_t xh_bytes = (size_t)M_DIM * K_DIM * 2;   // 64 MB
    const size_t wh_bytes = (size_t)N_DIM * K_DIM * 2;   // 32 MB

    if (ws_size >= xh_bytes + wh_bytes) {
        _Float16* xh = (_Float16*)d_ws;
        _Float16* wh = (_Float16*)((char*)d_ws + xh_bytes);
        prep_kernel<<<16384 + 8192, 256, 0, stream>>>(x, xh, w, wsc, wh);
        gemm_f16_pf<<<(M_DIM / BM) * (N_DIM / BN), 512, 0, stream>>>(xh, wh, bias, out);
    } else {
        fallback_kernel<<<((long)M_DIM * N_DIM) / 256, 256, 0, stream>>>(x, w, wsc, bias, out);
    }
}